// Round 1
// baseline (396.028 us; speedup 1.0000x reference)
//
#include <hip/hip_runtime.h>
#include <hip/hip_bf16.h>

#define BSZ   2048
#define KDIM  9408
#define NPROJ 1024
#define D1    2048
#define NCLS  65
#define DFC   3072

using bf16x8 = __attribute__((ext_vector_type(8))) short;
using f32x4  = __attribute__((ext_vector_type(4))) float;

__device__ __forceinline__ short f2bf(float f) {
    __hip_bfloat16 h = __float2bfloat16(f);
    return __builtin_bit_cast(short, h);
}

// ---------------------------------------------------------------------------
// Main GEMM: C[i,o] = sum_k z2f[i,k] * W_proj[o,k]   (both row-major over K)
// 128x128 tile, BK=64, 4 waves (2x2), mfma_f32_16x16x32_bf16, on-the-fly
// f32->bf16 convert in staging, XOR-swizzled LDS (write & read sides match).
// KS>1: store f32 partials to Cpart[ks][i][o].
// KS==1: fused bias+relu+column-sum epilogue -> atomic colsum.
// ---------------------------------------------------------------------------
template<int KS>
__global__ __launch_bounds__(256, 2)
void gemm_relu(const float* __restrict__ A,    // z2 flat [2048][9408]
               const float* __restrict__ B,    // W_proj  [1024][9408]
               const float* __restrict__ bias, // b_proj  [1024]
               float* __restrict__ Cpart,      // [KS][2048][1024]
               float* __restrict__ colsum)     // [1024]
{
    __shared__ __align__(16) short Alds[128 * 64];
    __shared__ __align__(16) short Blds[128 * 64];

    const int t  = threadIdx.x;
    const int bm = blockIdx.x, bn = blockIdx.y, ks = blockIdx.z;
    const int nsteps = 147 / KS;

    const int l  = t & 63, w = t >> 6;
    const int wr = w >> 1, wc = w & 1;
    const int lr = l & 15, lg = l >> 4;

    // staging coords: thread covers 8 consecutive f32 of one row
    const int srow = t >> 3;          // 0..31
    const int scol = (t & 7) * 8;     // 0..56
    const int sswz = (srow & 7) * 8;  // per-thread-constant LDS swizzle
    const int rswz = (lr & 7) * 8;    // read-side swizzle (row&7 == lr&7)

    const float* ga = A + (size_t)(bm * 128 + srow) * KDIM + scol;
    const float* gb = B + (size_t)(bn * 128 + srow) * KDIM + scol;

    f32x4 acc[4][4];
#pragma unroll
    for (int m = 0; m < 4; ++m)
#pragma unroll
        for (int n = 0; n < 4; ++n)
            acc[m][n] = (f32x4){0.f, 0.f, 0.f, 0.f};

    for (int step = 0; step < nsteps; ++step) {
        const int k0 = (ks * nsteps + step) * 64;

        // ---- stage A and B tiles (f32 global -> bf16 LDS, swizzled) ----
#pragma unroll
        for (int p = 0; p < 4; ++p) {
            const float* g = ga + (size_t)(p * 32) * KDIM + k0;
            float4 v0 = *(const float4*)g;
            float4 v1 = *(const float4*)(g + 4);
            bf16x8 s;
            s[0] = f2bf(v0.x); s[1] = f2bf(v0.y); s[2] = f2bf(v0.z); s[3] = f2bf(v0.w);
            s[4] = f2bf(v1.x); s[5] = f2bf(v1.y); s[6] = f2bf(v1.z); s[7] = f2bf(v1.w);
            *(bf16x8*)&Alds[(p * 32 + srow) * 64 + (scol ^ sswz)] = s;
        }
#pragma unroll
        for (int p = 0; p < 4; ++p) {
            const float* g = gb + (size_t)(p * 32) * KDIM + k0;
            float4 v0 = *(const float4*)g;
            float4 v1 = *(const float4*)(g + 4);
            bf16x8 s;
            s[0] = f2bf(v0.x); s[1] = f2bf(v0.y); s[2] = f2bf(v0.z); s[3] = f2bf(v0.w);
            s[4] = f2bf(v1.x); s[5] = f2bf(v1.y); s[6] = f2bf(v1.z); s[7] = f2bf(v1.w);
            *(bf16x8*)&Blds[(p * 32 + srow) * 64 + (scol ^ sswz)] = s;
        }
        __syncthreads();

        // ---- MFMA over the K=64 tile ----
#pragma unroll
        for (int kk = 0; kk < 2; ++kk) {
            const int kb = (kk * 32 + lg * 8) ^ rswz;
            bf16x8 af[4], bfr[4];
#pragma unroll
            for (int m = 0; m < 4; ++m)
                af[m] = *(bf16x8*)&Alds[(wr * 64 + m * 16 + lr) * 64 + kb];
#pragma unroll
            for (int n = 0; n < 4; ++n)
                bfr[n] = *(bf16x8*)&Blds[(wc * 64 + n * 16 + lr) * 64 + kb];
#pragma unroll
            for (int m = 0; m < 4; ++m)
#pragma unroll
                for (int n = 0; n < 4; ++n)
                    acc[m][n] = __builtin_amdgcn_mfma_f32_16x16x32_bf16(
                        af[m], bfr[n], acc[m][n], 0, 0, 0);
        }
        __syncthreads();
    }

    if constexpr (KS == 1) {
        // fused epilogue: bias + relu + block column-sum -> global atomic
        __shared__ float cls[128];
        if (t < 128) cls[t] = 0.f;
        __syncthreads();
#pragma unroll
        for (int n = 0; n < 4; ++n) {
            const int o = wc * 64 + n * 16 + lr;
            const float bv = bias[bn * 128 + o];
            float ps = 0.f;
#pragma unroll
            for (int m = 0; m < 4; ++m)
#pragma unroll
                for (int r = 0; r < 4; ++r) {
                    float v = acc[m][n][r] + bv;
                    ps += v > 0.f ? v : 0.f;
                }
            atomicAdd(&cls[o], ps);
        }
        __syncthreads();
        if (t < 128) atomicAdd(&colsum[bn * 128 + t], cls[t]);
    } else {
        float* Cp = Cpart + ((size_t)ks * BSZ + bm * 128) * NPROJ + bn * 128;
#pragma unroll
        for (int m = 0; m < 4; ++m)
#pragma unroll
            for (int r = 0; r < 4; ++r) {
                const int i = wr * 64 + m * 16 + lg * 4 + r;
#pragma unroll
                for (int n = 0; n < 4; ++n)
                    Cp[(size_t)i * NPROJ + wc * 64 + n * 16 + lr] = acc[m][n][r];
            }
    }
}

// sum split-K partials, add bias, relu, column-sum -> atomic colsum
template<int KS>
__global__ void reduce_colsum(const float* __restrict__ Cpart,
                              const float* __restrict__ bias,
                              float* __restrict__ colsum)
{
    const int t  = threadIdx.x;        // 256
    const int o0 = t * 4;
    const int r0 = blockIdx.x * 32;    // 64 blocks x 32 rows
    float4 bv = *(const float4*)&bias[o0];
    float p0 = 0.f, p1 = 0.f, p2 = 0.f, p3 = 0.f;
    for (int r = 0; r < 32; ++r) {
        const size_t i = (size_t)(r0 + r);
        float4 s = bv;
#pragma unroll
        for (int si = 0; si < KS; ++si) {
            float4 v = *(const float4*)&Cpart[((size_t)si * BSZ + i) * NPROJ + o0];
            s.x += v.x; s.y += v.y; s.z += v.z; s.w += v.w;
        }
        p0 += fmaxf(s.x, 0.f); p1 += fmaxf(s.y, 0.f);
        p2 += fmaxf(s.z, 0.f); p3 += fmaxf(s.w, 0.f);
    }
    atomicAdd(&colsum[o0 + 0], p0);
    atomicAdd(&colsum[o0 + 1], p1);
    atomicAdd(&colsum[o0 + 2], p2);
    atomicAdd(&colsum[o0 + 3], p3);
}

// sconst[c] = colsum . W_fc[c, 2048:] + 2048*b_fc[c]
__global__ void sconst_kernel(const float* __restrict__ colsum,
                              const float* __restrict__ Wfc,
                              const float* __restrict__ bfc,
                              float* __restrict__ sconst)
{
    const int c = blockIdx.x;      // 65
    const int l = threadIdx.x;     // 64
    const float* wr = Wfc + (size_t)c * DFC + D1;
    float p = 0.f;
#pragma unroll
    for (int j = 0; j < 16; ++j)
        p += colsum[l + j * 64] * wr[l + j * 64];
#pragma unroll
    for (int off = 32; off; off >>= 1)
        p += __shfl_xor(p, off);
    if (l == 0) sconst[c] = p + 2048.0f * bfc[c];
}

// out[i,c] = 2048*(z1[i,:] . W_fc[c,:2048]) + sconst[c]
// one wave per row; z1 row held in registers (32 VGPR)
__global__ __launch_bounds__(256)
void fc1_kernel(const float* __restrict__ z1,
                const float* __restrict__ Wfc,
                const float* __restrict__ sconst,
                float* __restrict__ out)
{
    const int l = threadIdx.x & 63;
    const int w = threadIdx.x >> 6;
    const int i = blockIdx.x * 4 + w;
    const float* zr = z1 + (size_t)i * D1;
    float4 za[8];
#pragma unroll
    for (int j = 0; j < 8; ++j)
        za[j] = *(const float4*)&zr[j * 256 + l * 4];
    for (int c = 0; c < NCLS; ++c) {
        const float* wrow = Wfc + (size_t)c * DFC;
        float acc = 0.f;
#pragma unroll
        for (int j = 0; j < 8; ++j) {
            float4 wv = *(const float4*)&wrow[j * 256 + l * 4];
            acc += za[j].x * wv.x + za[j].y * wv.y + za[j].z * wv.z + za[j].w * wv.w;
        }
#pragma unroll
        for (int off = 32; off; off >>= 1)
            acc += __shfl_xor(acc, off);
        if (l == 0) out[(size_t)i * NCLS + c] = 2048.0f * acc + sconst[c];
    }
}

extern "C" void kernel_launch(void* const* d_in, const int* in_sizes, int n_in,
                              void* d_out, int out_size, void* d_ws, size_t ws_size,
                              hipStream_t stream)
{
    (void)in_sizes; (void)n_in; (void)out_size;
    const float* z1  = (const float*)d_in[0];
    const float* z2  = (const float*)d_in[1];
    const float* Wp  = (const float*)d_in[2];
    const float* bp  = (const float*)d_in[3];
    const float* Wf  = (const float*)d_in[4];
    const float* bfc = (const float*)d_in[5];
    float* out = (float*)d_out;

    float* colsum = (float*)d_ws;                       // 1024 f32
    float* sconst = (float*)d_ws + 1024;                // 65 f32
    float* Cpart  = (float*)((char*)d_ws + 8192);       // KS*2048*1024 f32
    const size_t per = (size_t)BSZ * NPROJ * sizeof(float);

    hipMemsetAsync(d_ws, 0, 8192, stream);              // zero colsum

    if (ws_size >= 8192 + 7 * per) {
        gemm_relu<7><<<dim3(16, 8, 7), 256, 0, stream>>>(z2, Wp, bp, Cpart, colsum);
        reduce_colsum<7><<<64, 256, 0, stream>>>(Cpart, bp, colsum);
    } else if (ws_size >= 8192 + 3 * per) {
        gemm_relu<3><<<dim3(16, 8, 3), 256, 0, stream>>>(z2, Wp, bp, Cpart, colsum);
        reduce_colsum<3><<<64, 256, 0, stream>>>(Cpart, bp, colsum);
    } else {
        gemm_relu<1><<<dim3(16, 8, 1), 256, 0, stream>>>(z2, Wp, bp, Cpart, colsum);
    }
    sconst_kernel<<<65, 64, 0, stream>>>(colsum, Wf, bfc, sconst);
    fc1_kernel<<<512, 256, 0, stream>>>(z1, Wf, sconst, out);
}

// Round 3
// 334.612 us; speedup vs baseline: 1.1835x; 1.1835x over previous
//
#include <hip/hip_runtime.h>
#include <hip/hip_bf16.h>
#include <stdint.h>

#define BSZ   2048
#define KDIM  9408
#define NPROJ 1024
#define D1    2048
#define NCLS  65
#define DFC   3072
#define KSTEPS 147   // KDIM / 64

using bf16x8 = __attribute__((ext_vector_type(8))) short;
using f32x4  = __attribute__((ext_vector_type(4))) float;

__device__ __forceinline__ short f2bf(float f) {
    __hip_bfloat16 h = __float2bfloat16(f);
    return __builtin_bit_cast(short, h);
}

// async global->LDS, 16B per lane. LDS dest is wave-uniform base + lane*16,
// so LDS layout must be linear in lane order (m104/m173).
__device__ __forceinline__ void gload16(const void* g, void* l) {
    __builtin_amdgcn_global_load_lds(
        (const __attribute__((address_space(1))) void*)g,
        (__attribute__((address_space(3))) void*)l, 16, 0, 0);
}

// f32 -> bf16 vectorized conversion (8 elems/thread/iter), grid-stride
__global__ void cvt_bf16(const float* __restrict__ src, short* __restrict__ dst, int n8)
{
    int i = blockIdx.x * blockDim.x + threadIdx.x;
    const int stride = gridDim.x * blockDim.x;
    for (; i < n8; i += stride) {
        const float4 v0 = *(const float4*)(src + (size_t)i * 8);
        const float4 v1 = *(const float4*)(src + (size_t)i * 8 + 4);
        bf16x8 s;
        s[0] = f2bf(v0.x); s[1] = f2bf(v0.y); s[2] = f2bf(v0.z); s[3] = f2bf(v0.w);
        s[4] = f2bf(v1.x); s[5] = f2bf(v1.y); s[6] = f2bf(v1.z); s[7] = f2bf(v1.w);
        *(bf16x8*)(dst + (size_t)i * 8) = s;
    }
}

// ---------------------------------------------------------------------------
// m97-structure GEMM: C[i,o] = sum_k A[i,k]*B[o,k], bf16 inputs, f32 partials.
// 128x128 tile, BK=64, 4 waves (2x2), global_load_lds width-16 staging,
// linear LDS, 2-barrier K-loop, XCD-chunked block swizzle.
// ---------------------------------------------------------------------------
template<int KS>
__global__ __launch_bounds__(256, 2)
void gemm_bf16(const short* __restrict__ A,    // [2048][9408] bf16
               const short* __restrict__ B,    // [1024][9408] bf16
               float* __restrict__ Cpart)      // [KS][2048][1024] f32
{
    __shared__ __align__(16) short Alds[128 * 64];
    __shared__ __align__(16) short Blds[128 * 64];

    const int t = threadIdx.x;
    // XCD-chunked swizzle (nwg = 128*KS, divisible by 8 -> bijective)
    const int cpx = (128 * KS) >> 3;
    int bid = blockIdx.x;
    bid = (bid & 7) * cpx + (bid >> 3);
    const int bm = bid & 15;
    const int bn = (bid >> 4) & 7;
    const int ks = bid >> 7;
    const int nsteps = KSTEPS / KS;

    const int l = t & 63, w = t >> 6;
    const int wr = w >> 1, wc = w & 1;
    const int lr = l & 15, lg = l >> 4;

    const int srow = t >> 3;          // staging row within 32-row chunk
    const int scol = (t & 7) * 8;     // staging col (bf16 elems)

    const short* ga = A + (size_t)(bm * 128) * KDIM;
    const short* gb = B + (size_t)(bn * 128) * KDIM;

    f32x4 acc[4][4];
#pragma unroll
    for (int m = 0; m < 4; ++m)
#pragma unroll
        for (int n = 0; n < 4; ++n)
            acc[m][n] = (f32x4){0.f, 0.f, 0.f, 0.f};

    for (int step = 0; step < nsteps; ++step) {
        const int k0 = (ks * nsteps + step) * 64;

        // ---- async stage A and B tiles (bf16, linear LDS) ----
#pragma unroll
        for (int p = 0; p < 4; ++p)
            gload16(ga + (size_t)(p * 32 + srow) * KDIM + k0 + scol,
                    (char*)Alds + p * 4096 + t * 16);
#pragma unroll
        for (int p = 0; p < 4; ++p)
            gload16(gb + (size_t)(p * 32 + srow) * KDIM + k0 + scol,
                    (char*)Blds + p * 4096 + t * 16);
        __syncthreads();   // compiler drains vmcnt before s_barrier

        // ---- MFMA over the K=64 tile ----
#pragma unroll
        for (int kk = 0; kk < 2; ++kk) {
            const int kb = kk * 32 + lg * 8;
            bf16x8 af[4], bfr[4];
#pragma unroll
            for (int m = 0; m < 4; ++m)
                af[m] = *(bf16x8*)&Alds[(wr * 64 + m * 16 + lr) * 64 + kb];
#pragma unroll
            for (int n = 0; n < 4; ++n)
                bfr[n] = *(bf16x8*)&Blds[(wc * 64 + n * 16 + lr) * 64 + kb];
#pragma unroll
            for (int m = 0; m < 4; ++m)
#pragma unroll
                for (int n = 0; n < 4; ++n)
                    acc[m][n] = __builtin_amdgcn_mfma_f32_16x16x32_bf16(
                        af[m], bfr[n], acc[m][n], 0, 0, 0);
        }
        __syncthreads();
    }

    float* Cp = Cpart + ((size_t)ks * BSZ + bm * 128) * NPROJ + bn * 128;
#pragma unroll
    for (int m = 0; m < 4; ++m)
#pragma unroll
        for (int r = 0; r < 4; ++r) {
            const int i = wr * 64 + m * 16 + lg * 4 + r;
#pragma unroll
            for (int n = 0; n < 4; ++n)
                Cp[(size_t)i * NPROJ + wc * 64 + n * 16 + lr] = acc[m][n][r];
        }
}

// ---------------------------------------------------------------------------
// Fallback GEMM (tier C/D): f32 inputs, on-the-fly convert (R1 version).
// ---------------------------------------------------------------------------
template<int KS>
__global__ __launch_bounds__(256, 2)
void gemm_relu_f32(const float* __restrict__ A, const float* __restrict__ B,
                   const float* __restrict__ bias, float* __restrict__ Cpart,
                   float* __restrict__ colsum)
{
    __shared__ __align__(16) short Alds[128 * 64];
    __shared__ __align__(16) short Blds[128 * 64];

    const int t  = threadIdx.x;
    const int bm = blockIdx.x, bn = blockIdx.y, ks = blockIdx.z;
    const int nsteps = KSTEPS / KS;
    const int l  = t & 63, w = t >> 6;
    const int wr = w >> 1, wc = w & 1;
    const int lr = l & 15, lg = l >> 4;
    const int srow = t >> 3, scol = (t & 7) * 8;
    const int sswz = (srow & 7) * 8;
    const int rswz = (lr & 7) * 8;

    const float* ga = A + (size_t)(bm * 128 + srow) * KDIM + scol;
    const float* gb = B + (size_t)(bn * 128 + srow) * KDIM + scol;

    f32x4 acc[4][4];
#pragma unroll
    for (int m = 0; m < 4; ++m)
#pragma unroll
        for (int n = 0; n < 4; ++n)
            acc[m][n] = (f32x4){0.f, 0.f, 0.f, 0.f};

    for (int step = 0; step < nsteps; ++step) {
        const int k0 = (ks * nsteps + step) * 64;
#pragma unroll
        for (int p = 0; p < 4; ++p) {
            const float* g = ga + (size_t)(p * 32) * KDIM + k0;
            float4 v0 = *(const float4*)g;
            float4 v1 = *(const float4*)(g + 4);
            bf16x8 s;
            s[0] = f2bf(v0.x); s[1] = f2bf(v0.y); s[2] = f2bf(v0.z); s[3] = f2bf(v0.w);
            s[4] = f2bf(v1.x); s[5] = f2bf(v1.y); s[6] = f2bf(v1.z); s[7] = f2bf(v1.w);
            *(bf16x8*)&Alds[(p * 32 + srow) * 64 + (scol ^ sswz)] = s;
        }
#pragma unroll
        for (int p = 0; p < 4; ++p) {
            const float* g = gb + (size_t)(p * 32) * KDIM + k0;
            float4 v0 = *(const float4*)g;
            float4 v1 = *(const float4*)(g + 4);
            bf16x8 s;
            s[0] = f2bf(v0.x); s[1] = f2bf(v0.y); s[2] = f2bf(v0.z); s[3] = f2bf(v0.w);
            s[4] = f2bf(v1.x); s[5] = f2bf(v1.y); s[6] = f2bf(v1.z); s[7] = f2bf(v1.w);
            *(bf16x8*)&Blds[(p * 32 + srow) * 64 + (scol ^ sswz)] = s;
        }
        __syncthreads();
#pragma unroll
        for (int kk = 0; kk < 2; ++kk) {
            const int kb = (kk * 32 + lg * 8) ^ rswz;
            bf16x8 af[4], bfr[4];
#pragma unroll
            for (int m = 0; m < 4; ++m)
                af[m] = *(bf16x8*)&Alds[(wr * 64 + m * 16 + lr) * 64 + kb];
#pragma unroll
            for (int n = 0; n < 4; ++n)
                bfr[n] = *(bf16x8*)&Blds[(wc * 64 + n * 16 + lr) * 64 + kb];
#pragma unroll
            for (int m = 0; m < 4; ++m)
#pragma unroll
                for (int n = 0; n < 4; ++n)
                    acc[m][n] = __builtin_amdgcn_mfma_f32_16x16x32_bf16(
                        af[m], bfr[n], acc[m][n], 0, 0, 0);
        }
        __syncthreads();
    }

    if constexpr (KS == 1) {
        __shared__ float cls[128];
        if (t < 128) cls[t] = 0.f;
        __syncthreads();
#pragma unroll
        for (int n = 0; n < 4; ++n) {
            const int o = wc * 64 + n * 16 + lr;
            const float bv = bias[bn * 128 + o];
            float ps = 0.f;
#pragma unroll
            for (int m = 0; m < 4; ++m)
#pragma unroll
                for (int r = 0; r < 4; ++r) {
                    float v = acc[m][n][r] + bv;
                    ps += v > 0.f ? v : 0.f;
                }
            atomicAdd(&cls[o], ps);
        }
        __syncthreads();
        if (t < 128) atomicAdd(&colsum[bn * 128 + t], cls[t]);
    } else {
        float* Cp = Cpart + ((size_t)ks * BSZ + bm * 128) * NPROJ + bn * 128;
#pragma unroll
        for (int m = 0; m < 4; ++m)
#pragma unroll
            for (int r = 0; r < 4; ++r) {
                const int i = wr * 64 + m * 16 + lg * 4 + r;
#pragma unroll
                for (int n = 0; n < 4; ++n)
                    Cp[(size_t)i * NPROJ + wc * 64 + n * 16 + lr] = acc[m][n][r];
            }
    }
}

// sum split-K partials + bias, relu, column-sum. grid (128, 4), 512 blocks.
template<int KS>
__global__ void reduce_colsum(const float* __restrict__ Cpart,
                              const float* __restrict__ bias,
                              float* __restrict__ colsum)
{
    const int col = blockIdx.y * 256 + threadIdx.x;
    const int r0  = blockIdx.x * 16;
    const float bv = bias[col];
    float p = 0.f;
    for (int r = 0; r < 16; ++r) {
        float s = bv;
#pragma unroll
        for (int si = 0; si < KS; ++si)
            s += Cpart[((size_t)si * BSZ + r0 + r) * NPROJ + col];
        p += fmaxf(s, 0.f);
    }
    atomicAdd(&colsum[col], p);
}

// sconst[c] = colsum . W_fc[c, 2048:] + 2048*b_fc[c]
__global__ void sconst_kernel(const float* __restrict__ colsum,
                              const float* __restrict__ Wfc,
                              const float* __restrict__ bfc,
                              float* __restrict__ sconst)
{
    const int c = blockIdx.x;
    const int l = threadIdx.x;
    const float* wr = Wfc + (size_t)c * DFC + D1;
    float p = 0.f;
#pragma unroll
    for (int j = 0; j < 16; ++j)
        p += colsum[l + j * 64] * wr[l + j * 64];
#pragma unroll
    for (int off = 32; off; off >>= 1)
        p += __shfl_xor(p, off);
    if (l == 0) sconst[c] = p + 2048.0f * bfc[c];
}

// out[i,c] = 2048*(z1[i,:] . W_fc[c,:2048]) + sconst[c]
// wave per row; all 4 waves of a block iterate the same class sequence so
// W_fc rows hit L1 (block-shared).
__global__ __launch_bounds__(256)
void fc1_kernel(const float* __restrict__ z1,
                const float* __restrict__ Wfc,
                const float* __restrict__ sconst,
                float* __restrict__ out)
{
    const int l = threadIdx.x & 63;
    const int w = threadIdx.x >> 6;
    const int i = blockIdx.x * 4 + w;
    const float* zr = z1 + (size_t)i * D1;
    float4 za[8];
#pragma unroll
    for (int j = 0; j < 8; ++j)
        za[j] = *(const float4*)&zr[j * 256 + l * 4];
    for (int c = 0; c < NCLS; ++c) {
        const float* wrow = Wfc + (size_t)c * DFC;
        float acc = 0.f;
#pragma unroll
        for (int j = 0; j < 8; ++j) {
            float4 wv = *(const float4*)&wrow[j * 256 + l * 4];
            acc += za[j].x * wv.x + za[j].y * wv.y + za[j].z * wv.z + za[j].w * wv.w;
        }
#pragma unroll
        for (int off = 32; off; off >>= 1)
            acc += __shfl_xor(acc, off);
        if (l == 0) out[(size_t)i * NCLS + c] = 2048.0f * acc + sconst[c];
    }
}

extern "C" void kernel_launch(void* const* d_in, const int* in_sizes, int n_in,
                              void* d_out, int out_size, void* d_ws, size_t ws_size,
                              hipStream_t stream)
{
    (void)in_sizes; (void)n_in; (void)out_size;
    const float* z1  = (const float*)d_in[0];
    const float* z2  = (const float*)d_in[1];
    const float* Wp  = (const float*)d_in[2];
    const float* bp  = (const float*)d_in[3];
    const float* Wf  = (const float*)d_in[4];
    const float* bfc = (const float*)d_in[5];
    float* out = (float*)d_out;

    float* colsum = (float*)d_ws;                       // 1024 f32
    float* sconst = (float*)d_ws + 1024;                // 65 f32
    char*  base   = (char*)d_ws + 8192;
    const size_t perKS = (size_t)BSZ * NPROJ * sizeof(float);   // 8 MB
    const size_t z2bf_sz = (size_t)BSZ * KDIM * 2;              // 38.5 MB
    const size_t wp_sz   = (size_t)NPROJ * KDIM * 2;            // 19.3 MB

    hipMemsetAsync(d_ws, 0, 8192, stream);              // zero colsum

    const size_t needA = 8192 + 7 * perKS + z2bf_sz + wp_sz;
    const size_t needB = 8192 + 3 * perKS + z2bf_sz + wp_sz;

    if (ws_size >= needA) {
        float* Cpart = (float*)base;
        short* z2bf  = (short*)(base + 7 * perKS);
        short* wpbf  = (short*)(base + 7 * perKS + z2bf_sz);
        cvt_bf16<<<2048, 256, 0, stream>>>(z2, z2bf, BSZ * KDIM / 8);
        cvt_bf16<<<1024, 256, 0, stream>>>(Wp, wpbf, NPROJ * KDIM / 8);
        gemm_bf16<7><<<896, 256, 0, stream>>>(z2bf, wpbf, Cpart);
        reduce_colsum<7><<<dim3(128, 4), 256, 0, stream>>>(Cpart, bp, colsum);
    } else if (ws_size >= needB) {
        float* Cpart = (float*)base;
        short* z2bf  = (short*)(base + 3 * perKS);
        short* wpbf  = (short*)(base + 3 * perKS + z2bf_sz);
        cvt_bf16<<<2048, 256, 0, stream>>>(z2, z2bf, BSZ * KDIM / 8);
        cvt_bf16<<<1024, 256, 0, stream>>>(Wp, wpbf, NPROJ * KDIM / 8);
        gemm_bf16<3><<<384, 256, 0, stream>>>(z2bf, wpbf, Cpart);
        reduce_colsum<3><<<dim3(128, 4), 256, 0, stream>>>(Cpart, bp, colsum);
    } else if (ws_size >= 8192 + 7 * perKS) {
        float* Cpart = (float*)base;
        gemm_relu_f32<7><<<dim3(16, 8, 7), 256, 0, stream>>>(z2, Wp, bp, Cpart, colsum);
        reduce_colsum<7><<<dim3(128, 4), 256, 0, stream>>>(Cpart, bp, colsum);
    } else {
        float* Cpart = (float*)base;
        gemm_relu_f32<1><<<dim3(16, 8, 1), 256, 0, stream>>>(z2, Wp, bp, Cpart, colsum);
    }
    sconst_kernel<<<65, 64, 0, stream>>>(colsum, Wf, bfc, sconst);
    fc1_kernel<<<512, 256, 0, stream>>>(z1, Wf, sconst, out);
}

// Round 5
// 249.419 us; speedup vs baseline: 1.5878x; 1.3416x over previous
//
#include <hip/hip_runtime.h>
#include <hip/hip_bf16.h>
#include <stdint.h>

#define BSZ   2048
#define KDIM  9408
#define NPROJ 1024
#define D1    2048
#define NCLS  65
#define NPAD  80
#define DFC   3072
#define KSTEPS 147   // KDIM / 64

using bf16x8 = __attribute__((ext_vector_type(8))) short;
using f32x4  = __attribute__((ext_vector_type(4))) float;

__device__ __forceinline__ short f2bf(float f) {
    __hip_bfloat16 h = __float2bfloat16(f);
    return __builtin_bit_cast(short, h);
}

// async global->LDS, 16B per lane. LDS dest is wave-uniform base + lane*16.
__device__ __forceinline__ void gload16(const void* g, void* l) {
    __builtin_amdgcn_global_load_lds(
        (const __attribute__((address_space(1))) void*)g,
        (__attribute__((address_space(3))) void*)l, 16, 0, 0);
}

// f32 -> bf16 vectorized conversion (8 elems/thread/iter), grid-stride
__global__ void cvt_bf16(const float* __restrict__ src, short* __restrict__ dst, int n8)
{
    int i = blockIdx.x * blockDim.x + threadIdx.x;
    const int stride = gridDim.x * blockDim.x;
    for (; i < n8; i += stride) {
        const float4 v0 = *(const float4*)(src + (size_t)i * 8);
        const float4 v1 = *(const float4*)(src + (size_t)i * 8 + 4);
        bf16x8 s;
        s[0] = f2bf(v0.x); s[1] = f2bf(v0.y); s[2] = f2bf(v0.z); s[3] = f2bf(v0.w);
        s[4] = f2bf(v1.x); s[5] = f2bf(v1.y); s[6] = f2bf(v1.z); s[7] = f2bf(v1.w);
        *(bf16x8*)(dst + (size_t)i * 8) = s;
    }
}

// W_fc[:, :2048] -> bf16 [80][2048], rows 65..79 zeroed. 80 blocks x 256.
__global__ void w1pad_kernel(const float* __restrict__ Wf, short* __restrict__ W1)
{
    const int chunk = blockIdx.x * 256 + threadIdx.x;   // 20480 chunks
    const int row = chunk >> 8;                          // 256 chunks/row
    const int col = (chunk & 255) * 8;
    bf16x8 s;
    if (row < NCLS) {
        const float* g = Wf + (size_t)row * DFC + col;
        float4 v0 = *(const float4*)g;
        float4 v1 = *(const float4*)(g + 4);
        s[0] = f2bf(v0.x); s[1] = f2bf(v0.y); s[2] = f2bf(v0.z); s[3] = f2bf(v0.w);
        s[4] = f2bf(v1.x); s[5] = f2bf(v1.y); s[6] = f2bf(v1.z); s[7] = f2bf(v1.w);
    } else {
        s = (bf16x8){0,0,0,0,0,0,0,0};
    }
    *(bf16x8*)(W1 + (size_t)row * D1 + col) = s;
}

// ---------------------------------------------------------------------------
// Main GEMM: m97 structure, bf16 inputs, f32 partials. 128x128 tile, BK=64,
// 4 waves (2x2), global_load_lds staging, linear LDS, XCD-chunked swizzle.
// ---------------------------------------------------------------------------
template<int KS>
__global__ __launch_bounds__(256, 2)
void gemm_bf16(const short* __restrict__ A,    // [2048][9408] bf16
               const short* __restrict__ B,    // [1024][9408] bf16
               float* __restrict__ Cpart)      // [KS][2048][1024] f32
{
    __shared__ __align__(16) short Alds[128 * 64];
    __shared__ __align__(16) short Blds[128 * 64];

    const int t = threadIdx.x;
    const int cpx = (128 * KS) >> 3;
    int bid = blockIdx.x;
    bid = (bid & 7) * cpx + (bid >> 3);
    const int bm = bid & 15;
    const int bn = (bid >> 4) & 7;
    const int ks = bid >> 7;
    const int nsteps = KSTEPS / KS;

    const int l = t & 63, w = t >> 6;
    const int wr = w >> 1, wc = w & 1;
    const int lr = l & 15, lg = l >> 4;

    const int srow = t >> 3;
    const int scol = (t & 7) * 8;

    const short* ga = A + (size_t)(bm * 128) * KDIM;
    const short* gb = B + (size_t)(bn * 128) * KDIM;

    f32x4 acc[4][4];
#pragma unroll
    for (int m = 0; m < 4; ++m)
#pragma unroll
        for (int n = 0; n < 4; ++n)
            acc[m][n] = (f32x4){0.f, 0.f, 0.f, 0.f};

    for (int step = 0; step < nsteps; ++step) {
        const int k0 = (ks * nsteps + step) * 64;

#pragma unroll
        for (int p = 0; p < 4; ++p)
            gload16(ga + (size_t)(p * 32 + srow) * KDIM + k0 + scol,
                    (char*)Alds + p * 4096 + t * 16);
#pragma unroll
        for (int p = 0; p < 4; ++p)
            gload16(gb + (size_t)(p * 32 + srow) * KDIM + k0 + scol,
                    (char*)Blds + p * 4096 + t * 16);
        __syncthreads();

#pragma unroll
        for (int kk = 0; kk < 2; ++kk) {
            const int kb = kk * 32 + lg * 8;
            bf16x8 af[4], bfr[4];
#pragma unroll
            for (int m = 0; m < 4; ++m)
                af[m] = *(bf16x8*)&Alds[(wr * 64 + m * 16 + lr) * 64 + kb];
#pragma unroll
            for (int n = 0; n < 4; ++n)
                bfr[n] = *(bf16x8*)&Blds[(wc * 64 + n * 16 + lr) * 64 + kb];
#pragma unroll
            for (int m = 0; m < 4; ++m)
#pragma unroll
                for (int n = 0; n < 4; ++n)
                    acc[m][n] = __builtin_amdgcn_mfma_f32_16x16x32_bf16(
                        af[m], bfr[n], acc[m][n], 0, 0, 0);
        }
        __syncthreads();
    }

    float* Cp = Cpart + ((size_t)ks * BSZ + bm * 128) * NPROJ + bn * 128;
#pragma unroll
    for (int m = 0; m < 4; ++m)
#pragma unroll
        for (int r = 0; r < 4; ++r) {
            const int i = wr * 64 + m * 16 + lg * 4 + r;
#pragma unroll
            for (int n = 0; n < 4; ++n)
                Cp[(size_t)i * NPROJ + wc * 64 + n * 16 + lr] = acc[m][n][r];
        }
}

// ---------------------------------------------------------------------------
// fc2 GEMM: s1part[ks][i][c] = sum_k z1[i,k]*W1[c,k]. M=2048, N=80, K=2048.
// Split-K=16 -> 256 blocks. A staged f32->bf16 in-kernel (z1 read once);
// B (bf16 [80][2048]) staged via global_load_lds. 4 waves, each 32 rows x 80.
// ---------------------------------------------------------------------------
template<int KS2>
__global__ __launch_bounds__(256, 2)
void fc2_gemm(const float* __restrict__ z1,   // [2048][2048] f32
              const short* __restrict__ W1,   // [80][2048] bf16
              float* __restrict__ Cp2)        // [KS2][2048][80] f32
{
    __shared__ __align__(16) short Alds[128 * 64];
    __shared__ __align__(16) short Blds[NPAD * 64];

    const int t  = threadIdx.x;
    const int bm = blockIdx.x & 15;
    const int ks = blockIdx.x >> 4;
    const int nsteps = (D1 / 64) / KS2;   // 2

    const int l = t & 63, w = t >> 6;
    const int lr = l & 15, lg = l >> 4;
    const int srow = t >> 3;
    const int scol = (t & 7) * 8;

    f32x4 acc[2][5];
#pragma unroll
    for (int m = 0; m < 2; ++m)
#pragma unroll
        for (int n = 0; n < 5; ++n)
            acc[m][n] = (f32x4){0.f, 0.f, 0.f, 0.f};

    for (int step = 0; step < nsteps; ++step) {
        const int k0 = (ks * nsteps + step) * 64;

        // A: f32 load -> bf16 -> LDS (linear [128][64])
#pragma unroll
        for (int p = 0; p < 4; ++p) {
            const int row = p * 32 + srow;
            const float* g = z1 + (size_t)(bm * 128 + row) * D1 + k0 + scol;
            float4 v0 = *(const float4*)g;
            float4 v1 = *(const float4*)(g + 4);
            bf16x8 s;
            s[0] = f2bf(v0.x); s[1] = f2bf(v0.y); s[2] = f2bf(v0.z); s[3] = f2bf(v0.w);
            s[4] = f2bf(v1.x); s[5] = f2bf(v1.y); s[6] = f2bf(v1.z); s[7] = f2bf(v1.w);
            *(bf16x8*)&Alds[row * 64 + scol] = s;
        }
        // B: gload16 linear [80][64]; 640 16B-chunks = 2 full rounds + half
#pragma unroll
        for (int p = 0; p < 2; ++p) {
            const int chunk = p * 256 + t;
            gload16(W1 + (size_t)(chunk >> 3) * D1 + k0 + (chunk & 7) * 8,
                    (char*)Blds + chunk * 16);
        }
        if (t < 128) {
            const int chunk = 512 + t;
            gload16(W1 + (size_t)(chunk >> 3) * D1 + k0 + (chunk & 7) * 8,
                    (char*)Blds + chunk * 16);
        }
        __syncthreads();

#pragma unroll
        for (int kk = 0; kk < 2; ++kk) {
            const int kb = kk * 32 + lg * 8;
            bf16x8 af[2], bfr[5];
#pragma unroll
            for (int m = 0; m < 2; ++m)
                af[m] = *(bf16x8*)&Alds[(w * 32 + m * 16 + lr) * 64 + kb];
#pragma unroll
            for (int n = 0; n < 5; ++n)
                bfr[n] = *(bf16x8*)&Blds[(n * 16 + lr) * 64 + kb];
#pragma unroll
            for (int m = 0; m < 2; ++m)
#pragma unroll
                for (int n = 0; n < 5; ++n)
                    acc[m][n] = __builtin_amdgcn_mfma_f32_16x16x32_bf16(
                        af[m], bfr[n], acc[m][n], 0, 0, 0);
        }
        __syncthreads();
    }

    float* C = Cp2 + ((size_t)ks * BSZ + bm * 128) * NPAD;
#pragma unroll
    for (int m = 0; m < 2; ++m)
#pragma unroll
        for (int r = 0; r < 4; ++r) {
            const int i = w * 32 + m * 16 + lg * 4 + r;
#pragma unroll
            for (int n = 0; n < 5; ++n)
                C[(size_t)i * NPAD + n * 16 + lr] = acc[m][n][r];
        }
}

// out[i,c] = 2048 * sum_ks Cp2[ks][i][c] + sconst[c].  1024 blocks x 256:
// block b covers rows 2b..2b+1, lanes c = t&127 (c<65 active).
template<int KS2>
__global__ void reduce2_kernel(const float* __restrict__ Cp2,
                               const float* __restrict__ sconst,
                               float* __restrict__ out)
{
    const int i = blockIdx.x * 2 + (threadIdx.x >> 7);
    const int c = threadIdx.x & 127;
    if (c >= NCLS) return;
    float s = 0.f;
#pragma unroll
    for (int ksi = 0; ksi < KS2; ++ksi)
        s += Cp2[((size_t)ksi * BSZ + i) * NPAD + c];
    out[(size_t)i * NCLS + c] = 2048.0f * s + sconst[c];
}

// ---------------------------------------------------------------------------
// Fallback GEMM (f32 inputs, on-the-fly convert) — used when ws is small.
// ---------------------------------------------------------------------------
template<int KS>
__global__ __launch_bounds__(256, 2)
void gemm_relu_f32(const float* __restrict__ A, const float* __restrict__ B,
                   const float* __restrict__ bias, float* __restrict__ Cpart,
                   float* __restrict__ colsum)
{
    __shared__ __align__(16) short Alds[128 * 64];
    __shared__ __align__(16) short Blds[128 * 64];

    const int t  = threadIdx.x;
    const int bm = blockIdx.x, bn = blockIdx.y, ks = blockIdx.z;
    const int nsteps = KSTEPS / KS;
    const int l  = t & 63, w = t >> 6;
    const int wr = w >> 1, wc = w & 1;
    const int lr = l & 15, lg = l >> 4;
    const int srow = t >> 3, scol = (t & 7) * 8;
    const int sswz = (srow & 7) * 8;
    const int rswz = (lr & 7) * 8;

    const float* ga = A + (size_t)(bm * 128 + srow) * KDIM + scol;
    const float* gb = B + (size_t)(bn * 128 + srow) * KDIM + scol;

    f32x4 acc[4][4];
#pragma unroll
    for (int m = 0; m < 4; ++m)
#pragma unroll
        for (int n = 0; n < 4; ++n)
            acc[m][n] = (f32x4){0.f, 0.f, 0.f, 0.f};

    for (int step = 0; step < nsteps; ++step) {
        const int k0 = (ks * nsteps + step) * 64;
#pragma unroll
        for (int p = 0; p < 4; ++p) {
            const float* g = ga + (size_t)(p * 32) * KDIM + k0;
            float4 v0 = *(const float4*)g;
            float4 v1 = *(const float4*)(g + 4);
            bf16x8 s;
            s[0] = f2bf(v0.x); s[1] = f2bf(v0.y); s[2] = f2bf(v0.z); s[3] = f2bf(v0.w);
            s[4] = f2bf(v1.x); s[5] = f2bf(v1.y); s[6] = f2bf(v1.z); s[7] = f2bf(v1.w);
            *(bf16x8*)&Alds[(p * 32 + srow) * 64 + (scol ^ sswz)] = s;
        }
#pragma unroll
        for (int p = 0; p < 4; ++p) {
            const float* g = gb + (size_t)(p * 32) * KDIM + k0;
            float4 v0 = *(const float4*)g;
            float4 v1 = *(const float4*)(g + 4);
            bf16x8 s;
            s[0] = f2bf(v0.x); s[1] = f2bf(v0.y); s[2] = f2bf(v0.z); s[3] = f2bf(v0.w);
            s[4] = f2bf(v1.x); s[5] = f2bf(v1.y); s[6] = f2bf(v1.z); s[7] = f2bf(v1.w);
            *(bf16x8*)&Blds[(p * 32 + srow) * 64 + (scol ^ sswz)] = s;
        }
        __syncthreads();
#pragma unroll
        for (int kk = 0; kk < 2; ++kk) {
            const int kb = (kk * 32 + lg * 8) ^ rswz;
            bf16x8 af[4], bfr[4];
#pragma unroll
            for (int m = 0; m < 4; ++m)
                af[m] = *(bf16x8*)&Alds[(wr * 64 + m * 16 + lr) * 64 + kb];
#pragma unroll
            for (int n = 0; n < 4; ++n)
                bfr[n] = *(bf16x8*)&Blds[(wc * 64 + n * 16 + lr) * 64 + kb];
#pragma unroll
            for (int m = 0; m < 4; ++m)
#pragma unroll
                for (int n = 0; n < 4; ++n)
                    acc[m][n] = __builtin_amdgcn_mfma_f32_16x16x32_bf16(
                        af[m], bfr[n], acc[m][n], 0, 0, 0);
        }
        __syncthreads();
    }

    if constexpr (KS == 1) {
        __shared__ float cls[128];
        if (t < 128) cls[t] = 0.f;
        __syncthreads();
#pragma unroll
        for (int n = 0; n < 4; ++n) {
            const int o = wc * 64 + n * 16 + lr;
            const float bv = bias[bn * 128 + o];
            float ps = 0.f;
#pragma unroll
            for (int m = 0; m < 4; ++m)
#pragma unroll
                for (int r = 0; r < 4; ++r) {
                    float v = acc[m][n][r] + bv;
                    ps += v > 0.f ? v : 0.f;
                }
            atomicAdd(&cls[o], ps);
        }
        __syncthreads();
        if (t < 128) atomicAdd(&colsum[bn * 128 + t], cls[t]);
    } else {
        float* Cp = Cpart + ((size_t)ks * BSZ + bm * 128) * NPROJ + bn * 128;
#pragma unroll
        for (int m = 0; m < 4; ++m)
#pragma unroll
            for (int r = 0; r < 4; ++r) {
                const int i = wr * 64 + m * 16 + lg * 4 + r;
#pragma unroll
                for (int n = 0; n < 4; ++n)
                    Cp[(size_t)i * NPROJ + wc * 64 + n * 16 + lr] = acc[m][n][r];
            }
    }
}

// sum split-K partials + bias, relu, column-sum. grid (128, 4), 512 blocks.
template<int KS>
__global__ void reduce_colsum(const float* __restrict__ Cpart,
                              const float* __restrict__ bias,
                              float* __restrict__ colsum)
{
    const int col = blockIdx.y * 256 + threadIdx.x;
    const int r0  = blockIdx.x * 16;
    const float bv = bias[col];
    float p = 0.f;
    for (int r = 0; r < 16; ++r) {
        float s = bv;
#pragma unroll
        for (int si = 0; si < KS; ++si)
            s += Cpart[((size_t)si * BSZ + r0 + r) * NPROJ + col];
        p += fmaxf(s, 0.f);
    }
    atomicAdd(&colsum[col], p);
}

// sconst[c] = colsum . W_fc[c, 2048:] + 2048*b_fc[c]
__global__ void sconst_kernel(const float* __restrict__ colsum,
                              const float* __restrict__ Wfc,
                              const float* __restrict__ bfc,
                              float* __restrict__ sconst)
{
    const int c = blockIdx.x;
    const int l = threadIdx.x;
    const float* wr = Wfc + (size_t)c * DFC + D1;
    float p = 0.f;
#pragma unroll
    for (int j = 0; j < 16; ++j)
        p += colsum[l + j * 64] * wr[l + j * 64];
#pragma unroll
    for (int off = 32; off; off >>= 1)
        p += __shfl_xor(p, off);
    if (l == 0) sconst[c] = p + 2048.0f * bfc[c];
}

// f32 fallback for fc path (no ws needed beyond sconst)
__global__ __launch_bounds__(256)
void fc1_kernel(const float* __restrict__ z1,
                const float* __restrict__ Wfc,
                const float* __restrict__ sconst,
                float* __restrict__ out)
{
    const int l = threadIdx.x & 63;
    const int w = threadIdx.x >> 6;
    const int i = blockIdx.x * 4 + w;
    const float* zr = z1 + (size_t)i * D1;
    float4 za[8];
#pragma unroll
    for (int j = 0; j < 8; ++j)
        za[j] = *(const float4*)&zr[j * 256 + l * 4];
    for (int c = 0; c < NCLS; ++c) {
        const float* wrow = Wfc + (size_t)c * DFC;
        float acc = 0.f;
#pragma unroll
        for (int j = 0; j < 8; ++j) {
            float4 wv = *(const float4*)&wrow[j * 256 + l * 4];
            acc += za[j].x * wv.x + za[j].y * wv.y + za[j].z * wv.z + za[j].w * wv.w;
        }
#pragma unroll
        for (int off = 32; off; off >>= 1)
            acc += __shfl_xor(acc, off);
        if (l == 0) out[(size_t)i * NCLS + c] = 2048.0f * acc + sconst[c];
    }
}

extern "C" void kernel_launch(void* const* d_in, const int* in_sizes, int n_in,
                              void* d_out, int out_size, void* d_ws, size_t ws_size,
                              hipStream_t stream)
{
    (void)in_sizes; (void)n_in; (void)out_size;
    const float* z1  = (const float*)d_in[0];
    const float* z2  = (const float*)d_in[1];
    const float* Wp  = (const float*)d_in[2];
    const float* bp  = (const float*)d_in[3];
    const float* Wf  = (const float*)d_in[4];
    const float* bfc = (const float*)d_in[5];
    float* out = (float*)d_out;

    float* colsum = (float*)d_ws;                 // 1024 f32
    float* sconst = (float*)d_ws + 1024;          // 65 f32
    size_t off = 8192;

    // --- fc2 buffers (highest priority; small) ---
    const size_t w1_sz = (size_t)NPAD * D1 * 2;            // 327,680
    const size_t c2_sz = (size_t)16 * BSZ * NPAD * 4;      // 10.5 MB
    const bool fc2_ok = ws_size >= off + w1_sz + c2_sz;
    short* W1  = (short*)((char*)d_ws + off);
    float* Cp2 = (float*)((char*)d_ws + off + w1_sz);
    if (fc2_ok) off += w1_sz + c2_sz;

    // --- main-GEMM buffers ---
    const size_t z2bf_sz = (size_t)BSZ * KDIM * 2;         // 38.5 MB
    const size_t wp_sz   = (size_t)NPROJ * KDIM * 2;       // 19.3 MB
    const size_t perKS   = (size_t)BSZ * NPROJ * 4;        // 8 MB
    const size_t rem = ws_size > off ? ws_size - off : 0;

    hipMemsetAsync(d_ws, 0, 8192, stream);        // zero colsum/sconst

    int main_ks = 0;                               // 0 = f32 fallback
    if      (rem >= z2bf_sz + wp_sz + 7 * perKS) main_ks = 7;
    else if (rem >= z2bf_sz + wp_sz + 3 * perKS) main_ks = 3;
    else if (rem >= z2bf_sz + wp_sz + 1 * perKS) main_ks = 1;

    if (main_ks > 0) {
        short* z2bf  = (short*)((char*)d_ws + off);
        short* wpbf  = (short*)((char*)d_ws + off + z2bf_sz);
        float* Cpart = (float*)((char*)d_ws + off + z2bf_sz + wp_sz);
        cvt_bf16<<<2048, 256, 0, stream>>>(z2, z2bf, BSZ * KDIM / 8);
        cvt_bf16<<<1024, 256, 0, stream>>>(Wp, wpbf, NPROJ * KDIM / 8);
        if (main_ks == 7) {
            gemm_bf16<7><<<896, 256, 0, stream>>>(z2bf, wpbf, Cpart);
            reduce_colsum<7><<<dim3(128, 4), 256, 0, stream>>>(Cpart, bp, colsum);
        } else if (main_ks == 3) {
            gemm_bf16<3><<<384, 256, 0, stream>>>(z2bf, wpbf, Cpart);
            reduce_colsum<3><<<dim3(128, 4), 256, 0, stream>>>(Cpart, bp, colsum);
        } else {
            gemm_bf16<1><<<128, 256, 0, stream>>>(z2bf, wpbf, Cpart);
            reduce_colsum<1><<<dim3(128, 4), 256, 0, stream>>>(Cpart, bp, colsum);
        }
    } else if (rem >= 7 * perKS) {
        float* Cpart = (float*)((char*)d_ws + off);
        gemm_relu_f32<7><<<dim3(16, 8, 7), 256, 0, stream>>>(z2, Wp, bp, Cpart, colsum);
        reduce_colsum<7><<<dim3(128, 4), 256, 0, stream>>>(Cpart, bp, colsum);
    } else {
        gemm_relu_f32<1><<<dim3(16, 8, 1), 256, 0, stream>>>(z2, Wp, bp,
                                                             (float*)((char*)d_ws + off), colsum);
    }

    sconst_kernel<<<65, 64, 0, stream>>>(colsum, Wf, bfc, sconst);

    if (fc2_ok) {
        w1pad_kernel<<<80, 256, 0, stream>>>(Wf, W1);
        fc2_gemm<16><<<256, 256, 0, stream>>>(z1, W1, Cp2);
        reduce2_kernel<16><<<1024, 256, 0, stream>>>(Cp2, sconst, out);
    } else {
        fc1_kernel<<<512, 256, 0, stream>>>(z1, Wf, sconst, out);
    }
}

// Round 8
// 234.316 us; speedup vs baseline: 1.6901x; 1.0645x over previous
//
#include <hip/hip_runtime.h>
#include <hip/hip_bf16.h>
#include <stdint.h>

#define BSZ   2048
#define KDIM  9408
#define NPROJ 1024
#define D1    2048
#define NCLS  65
#define NPAD  80
#define DFC   3072
#define KSTEPS 147   // KDIM / 64

using bf16x8 = __attribute__((ext_vector_type(8))) short;
using f32x4  = __attribute__((ext_vector_type(4))) float;

__device__ __forceinline__ short f2bf(float f) {
    __hip_bfloat16 h = __float2bfloat16(f);
    return __builtin_bit_cast(short, h);
}

// async global->LDS, 16B per lane. LDS dest is wave-uniform base + lane*16.
__device__ __forceinline__ void gload16(const void* g, void* l) {
    __builtin_amdgcn_global_load_lds(
        (const __attribute__((address_space(1))) void*)g,
        (__attribute__((address_space(3))) void*)l, 16, 0, 0);
}

__device__ __forceinline__ bf16x8 cvt8(const float* g) {
    float4 v0 = *(const float4*)g;
    float4 v1 = *(const float4*)(g + 4);
    bf16x8 s;
    s[0] = f2bf(v0.x); s[1] = f2bf(v0.y); s[2] = f2bf(v0.z); s[3] = f2bf(v0.w);
    s[4] = f2bf(v1.x); s[5] = f2bf(v1.y); s[6] = f2bf(v1.z); s[7] = f2bf(v1.w);
    return s;
}

// ---------------------------------------------------------------------------
// fused_cvt: one grid-stride kernel doing (1) z2 f32->bf16, (2) W_proj
// f32->bf16, (3) W_fc[:, :2048] -> bf16 [80][2048] padded, (4) zero colsum.
// ---------------------------------------------------------------------------
#define NC_Z2 (BSZ * KDIM / 8)       // 2,408,448
#define NC_WP (NPROJ * KDIM / 8)     // 1,204,224
#define NC_W1 (NPAD * D1 / 8)        //    20,480
#define NC_TOT (NC_Z2 + NC_WP + NC_W1)

__global__ void fused_cvt(const float* __restrict__ z2, short* __restrict__ z2bf,
                          const float* __restrict__ Wp, short* __restrict__ wpbf,
                          const float* __restrict__ Wf, short* __restrict__ W1,
                          float* __restrict__ wshead)
{
    const int gid = blockIdx.x * blockDim.x + threadIdx.x;
    if (gid < 2048) wshead[gid] = 0.f;     // colsum + sconst zero-init
    const int stride = gridDim.x * blockDim.x;
    for (int i = gid; i < NC_TOT; i += stride) {
        if (i < NC_Z2) {
            *(bf16x8*)(z2bf + (size_t)i * 8) = cvt8(z2 + (size_t)i * 8);
        } else if (i < NC_Z2 + NC_WP) {
            const int j = i - NC_Z2;
            *(bf16x8*)(wpbf + (size_t)j * 8) = cvt8(Wp + (size_t)j * 8);
        } else {
            const int c = i - NC_Z2 - NC_WP;     // [0, 20480)
            const int row = c >> 8;              // 0..79
            const int col = (c & 255) * 8;
            bf16x8 s = (bf16x8){0,0,0,0,0,0,0,0};
            if (row < NCLS) s = cvt8(Wf + (size_t)row * DFC + col);
            *(bf16x8*)(W1 + (size_t)row * D1 + col) = s;
        }
    }
}

// ---------------------------------------------------------------------------
// gemm_combo: blocks [0, 128*KS) = main GEMM (m97 structure, 128x128, BK=64,
// global_load_lds, XCD-chunked swizzle); blocks [128*KS, +256) = fc2 GEMM
// (M=2048, N=80, K=2048, split-K=16). Shared 32 KB LDS.
// ---------------------------------------------------------------------------
template<int KS>
__global__ __launch_bounds__(256, 4)
void gemm_combo(const short* __restrict__ A,    // z2bf [2048][9408]
                const short* __restrict__ B,    // wpbf [1024][9408]
                float* __restrict__ Cpart,      // [KS][2048][1024]
                const float* __restrict__ z1,   // [2048][2048] f32
                const short* __restrict__ W1,   // [80][2048] bf16
                float* __restrict__ Cp2)        // [16][2048][80]
{
    __shared__ __align__(16) char smem[32768];
    short* Alds = (short*)smem;                 // [128*64]
    short* Blds = (short*)(smem + 16384);       // main [128*64] / fc2 [80*64]

    const int t = threadIdx.x;
    const int l = t & 63, w = t >> 6;
    const int lr = l & 15, lg = l >> 4;
    const int srow = t >> 3;
    const int scol = (t & 7) * 8;

    if (blockIdx.x < 128 * KS) {
        // ---------------- main GEMM ----------------
        const int cpx = (128 * KS) >> 3;
        int bid = blockIdx.x;
        bid = (bid & 7) * cpx + (bid >> 3);
        const int bm = bid & 15;
        const int bn = (bid >> 4) & 7;
        const int ks = bid >> 7;
        const int nsteps = KSTEPS / KS;

        const int wr = w >> 1, wc = w & 1;
        const short* ga = A + (size_t)(bm * 128) * KDIM;
        const short* gb = B + (size_t)(bn * 128) * KDIM;

        f32x4 acc[4][4];
#pragma unroll
        for (int m = 0; m < 4; ++m)
#pragma unroll
            for (int n = 0; n < 4; ++n)
                acc[m][n] = (f32x4){0.f, 0.f, 0.f, 0.f};

        for (int step = 0; step < nsteps; ++step) {
            const int k0 = (ks * nsteps + step) * 64;
#pragma unroll
            for (int p = 0; p < 4; ++p)
                gload16(ga + (size_t)(p * 32 + srow) * KDIM + k0 + scol,
                        (char*)Alds + p * 4096 + t * 16);
#pragma unroll
            for (int p = 0; p < 4; ++p)
                gload16(gb + (size_t)(p * 32 + srow) * KDIM + k0 + scol,
                        (char*)Blds + p * 4096 + t * 16);
            __syncthreads();

#pragma unroll
            for (int kk = 0; kk < 2; ++kk) {
                const int kb = kk * 32 + lg * 8;
                bf16x8 af[4], bfr[4];
#pragma unroll
                for (int m = 0; m < 4; ++m)
                    af[m] = *(bf16x8*)&Alds[(wr * 64 + m * 16 + lr) * 64 + kb];
#pragma unroll
                for (int n = 0; n < 4; ++n)
                    bfr[n] = *(bf16x8*)&Blds[(wc * 64 + n * 16 + lr) * 64 + kb];
#pragma unroll
                for (int m = 0; m < 4; ++m)
#pragma unroll
                    for (int n = 0; n < 4; ++n)
                        acc[m][n] = __builtin_amdgcn_mfma_f32_16x16x32_bf16(
                            af[m], bfr[n], acc[m][n], 0, 0, 0);
            }
            __syncthreads();
        }

        float* Cp = Cpart + ((size_t)ks * BSZ + bm * 128) * NPROJ + bn * 128;
#pragma unroll
        for (int m = 0; m < 4; ++m)
#pragma unroll
            for (int r = 0; r < 4; ++r) {
                const int i = wr * 64 + m * 16 + lg * 4 + r;
#pragma unroll
                for (int n = 0; n < 4; ++n)
                    Cp[(size_t)i * NPROJ + wc * 64 + n * 16 + lr] = acc[m][n][r];
            }
    } else {
        // ---------------- fc2 GEMM (KS2 = 16) ----------------
        const int fbid = blockIdx.x - 128 * KS;
        const int bm = fbid & 15;
        const int ks = fbid >> 4;

        f32x4 acc[2][5];
#pragma unroll
        for (int m = 0; m < 2; ++m)
#pragma unroll
            for (int n = 0; n < 5; ++n)
                acc[m][n] = (f32x4){0.f, 0.f, 0.f, 0.f};

#pragma unroll
        for (int step = 0; step < 2; ++step) {
            const int k0 = (ks * 2 + step) * 64;

            // A: f32 load -> bf16 -> LDS (linear [128][64])
#pragma unroll
            for (int p = 0; p < 4; ++p) {
                const int row = p * 32 + srow;
                *(bf16x8*)&Alds[row * 64 + scol] =
                    cvt8(z1 + (size_t)(bm * 128 + row) * D1 + k0 + scol);
            }
            // B: gload16 linear [80][64]; 640 16B-chunks
#pragma unroll
            for (int p = 0; p < 2; ++p) {
                const int chunk = p * 256 + t;
                gload16(W1 + (size_t)(chunk >> 3) * D1 + k0 + (chunk & 7) * 8,
                        (char*)Blds + chunk * 16);
            }
            if (t < 128) {
                const int chunk = 512 + t;
                gload16(W1 + (size_t)(chunk >> 3) * D1 + k0 + (chunk & 7) * 8,
                        (char*)Blds + chunk * 16);
            }
            __syncthreads();

#pragma unroll
            for (int kk = 0; kk < 2; ++kk) {
                const int kb = kk * 32 + lg * 8;
                bf16x8 af[2], bfr[5];
#pragma unroll
                for (int m = 0; m < 2; ++m)
                    af[m] = *(bf16x8*)&Alds[(w * 32 + m * 16 + lr) * 64 + kb];
#pragma unroll
                for (int n = 0; n < 5; ++n)
                    bfr[n] = *(bf16x8*)&Blds[(n * 16 + lr) * 64 + kb];
#pragma unroll
                for (int m = 0; m < 2; ++m)
#pragma unroll
                    for (int n = 0; n < 5; ++n)
                        acc[m][n] = __builtin_amdgcn_mfma_f32_16x16x32_bf16(
                            af[m], bfr[n], acc[m][n], 0, 0, 0);
            }
            __syncthreads();
        }

        float* C = Cp2 + ((size_t)ks * BSZ + bm * 128) * NPAD;
#pragma unroll
        for (int m = 0; m < 2; ++m)
#pragma unroll
            for (int r = 0; r < 4; ++r) {
                const int i = w * 32 + m * 16 + lg * 4 + r;
#pragma unroll
                for (int n = 0; n < 5; ++n)
                    C[(size_t)i * NPAD + n * 16 + lr] = acc[m][n][r];
            }
    }
}

// sum split-K partials + bias, relu, column-sum. grid (128, 4), 512 blocks.
template<int KS>
__global__ void reduce_colsum(const float* __restrict__ Cpart,
                              const float* __restrict__ bias,
                              float* __restrict__ colsum)
{
    const int col = blockIdx.y * 256 + threadIdx.x;
    const int r0  = blockIdx.x * 16;
    const float bv = bias[col];
    float p = 0.f;
    for (int r = 0; r < 16; ++r) {
        float s = bv;
#pragma unroll
        for (int si = 0; si < KS; ++si)
            s += Cpart[((size_t)si * BSZ + r0 + r) * NPROJ + col];
        p += fmaxf(s, 0.f);
    }
    atomicAdd(&colsum[col], p);
}

// sconst[c] = colsum . W_fc[c, 2048:] + 2048*b_fc[c]
__global__ void sconst_kernel(const float* __restrict__ colsum,
                              const float* __restrict__ Wfc,
                              const float* __restrict__ bfc,
                              float* __restrict__ sconst)
{
    const int c = blockIdx.x;
    const int l = threadIdx.x;
    const float* wr = Wfc + (size_t)c * DFC + D1;
    float p = 0.f;
#pragma unroll
    for (int j = 0; j < 16; ++j)
        p += colsum[l + j * 64] * wr[l + j * 64];
#pragma unroll
    for (int off = 32; off; off >>= 1)
        p += __shfl_xor(p, off);
    if (l == 0) sconst[c] = p + 2048.0f * bfc[c];
}

// out[i,c] = 2048 * sum_ks Cp2[ks][i][c] + sconst[c]. 1024 blocks x 256.
template<int KS2>
__global__ void reduce2_kernel(const float* __restrict__ Cp2,
                               const float* __restrict__ sconst,
                               float* __restrict__ out)
{
    const int i = blockIdx.x * 2 + (threadIdx.x >> 7);
    const int c = threadIdx.x & 127;
    if (c >= NCLS) return;
    float s = 0.f;
#pragma unroll
    for (int ksi = 0; ksi < KS2; ++ksi)
        s += Cp2[((size_t)ksi * BSZ + i) * NPAD + c];
    out[(size_t)i * NCLS + c] = 2048.0f * s + sconst[c];
}

// ===========================================================================
// Fallback kernels (smaller ws tiers) — R4-validated paths.
// ===========================================================================
__global__ void cvt_bf16(const float* __restrict__ src, short* __restrict__ dst, int n8)
{
    int i = blockIdx.x * blockDim.x + threadIdx.x;
    const int stride = gridDim.x * blockDim.x;
    for (; i < n8; i += stride)
        *(bf16x8*)(dst + (size_t)i * 8) = cvt8(src + (size_t)i * 8);
}

__global__ void w1pad_kernel(const float* __restrict__ Wf, short* __restrict__ W1)
{
    const int chunk = blockIdx.x * 256 + threadIdx.x;
    const int row = chunk >> 8;
    const int col = (chunk & 255) * 8;
    bf16x8 s = (bf16x8){0,0,0,0,0,0,0,0};
    if (row < NCLS) s = cvt8(Wf + (size_t)row * DFC + col);
    *(bf16x8*)(W1 + (size_t)row * D1 + col) = s;
}

template<int KS>
__global__ __launch_bounds__(256, 2)
void gemm_bf16(const short* __restrict__ A, const short* __restrict__ B,
               float* __restrict__ Cpart)
{
    __shared__ __align__(16) short Alds[128 * 64];
    __shared__ __align__(16) short Blds[128 * 64];
    const int t = threadIdx.x;
    const int cpx = (128 * KS) >> 3;
    int bid = blockIdx.x;
    bid = (bid & 7) * cpx + (bid >> 3);
    const int bm = bid & 15;
    const int bn = (bid >> 4) & 7;
    const int ks = bid >> 7;
    const int nsteps = KSTEPS / KS;
    const int l = t & 63, w = t >> 6;
    const int wr = w >> 1, wc = w & 1;
    const int lr = l & 15, lg = l >> 4;
    const int srow = t >> 3, scol = (t & 7) * 8;
    const short* ga = A + (size_t)(bm * 128) * KDIM;
    const short* gb = B + (size_t)(bn * 128) * KDIM;
    f32x4 acc[4][4];
#pragma unroll
    for (int m = 0; m < 4; ++m)
#pragma unroll
        for (int n = 0; n < 4; ++n) acc[m][n] = (f32x4){0.f,0.f,0.f,0.f};
    for (int step = 0; step < nsteps; ++step) {
        const int k0 = (ks * nsteps + step) * 64;
#pragma unroll
        for (int p = 0; p < 4; ++p)
            gload16(ga + (size_t)(p * 32 + srow) * KDIM + k0 + scol,
                    (char*)Alds + p * 4096 + t * 16);
#pragma unroll
        for (int p = 0; p < 4; ++p)
            gload16(gb + (size_t)(p * 32 + srow) * KDIM + k0 + scol,
                    (char*)Blds + p * 4096 + t * 16);
        __syncthreads();
#pragma unroll
        for (int kk = 0; kk < 2; ++kk) {
            const int kb = kk * 32 + lg * 8;
            bf16x8 af[4], bfr[4];
#pragma unroll
            for (int m = 0; m < 4; ++m)
                af[m] = *(bf16x8*)&Alds[(wr * 64 + m * 16 + lr) * 64 + kb];
#pragma unroll
            for (int n = 0; n < 4; ++n)
                bfr[n] = *(bf16x8*)&Blds[(wc * 64 + n * 16 + lr) * 64 + kb];
#pragma unroll
            for (int m = 0; m < 4; ++m)
#pragma unroll
                for (int n = 0; n < 4; ++n)
                    acc[m][n] = __builtin_amdgcn_mfma_f32_16x16x32_bf16(
                        af[m], bfr[n], acc[m][n], 0, 0, 0);
        }
        __syncthreads();
    }
    float* Cp = Cpart + ((size_t)ks * BSZ + bm * 128) * NPROJ + bn * 128;
#pragma unroll
    for (int m = 0; m < 4; ++m)
#pragma unroll
        for (int r = 0; r < 4; ++r) {
            const int i = wr * 64 + m * 16 + lg * 4 + r;
#pragma unroll
            for (int n = 0; n < 4; ++n)
                Cp[(size_t)i * NPROJ + wc * 64 + n * 16 + lr] = acc[m][n][r];
        }
}

template<int KS2>
__global__ __launch_bounds__(256, 2)
void fc2_gemm(const float* __restrict__ z1, const short* __restrict__ W1,
              float* __restrict__ Cp2)
{
    __shared__ __align__(16) short Alds[128 * 64];
    __shared__ __align__(16) short Blds[NPAD * 64];
    const int t  = threadIdx.x;
    const int bm = blockIdx.x & 15;
    const int ks = blockIdx.x >> 4;
    const int nsteps = (D1 / 64) / KS2;
    const int l = t & 63, w = t >> 6;
    const int lr = l & 15, lg = l >> 4;
    const int srow = t >> 3, scol = (t & 7) * 8;
    f32x4 acc[2][5];
#pragma unroll
    for (int m = 0; m < 2; ++m)
#pragma unroll
        for (int n = 0; n < 5; ++n) acc[m][n] = (f32x4){0.f,0.f,0.f,0.f};
    for (int step = 0; step < nsteps; ++step) {
        const int k0 = (ks * nsteps + step) * 64;
#pragma unroll
        for (int p = 0; p < 4; ++p) {
            const int row = p * 32 + srow;
            *(bf16x8*)&Alds[row * 64 + scol] =
                cvt8(z1 + (size_t)(bm * 128 + row) * D1 + k0 + scol);
        }
#pragma unroll
        for (int p = 0; p < 2; ++p) {
            const int chunk = p * 256 + t;
            gload16(W1 + (size_t)(chunk >> 3) * D1 + k0 + (chunk & 7) * 8,
                    (char*)Blds + chunk * 16);
        }
        if (t < 128) {
            const int chunk = 512 + t;
            gload16(W1 + (size_t)(chunk >> 3) * D1 + k0 + (chunk & 7) * 8,
                    (char*)Blds + chunk * 16);
        }
        __syncthreads();
#pragma unroll
        for (int kk = 0; kk < 2; ++kk) {
            const int kb = kk * 32 + lg * 8;
            bf16x8 af[2], bfr[5];
#pragma unroll
            for (int m = 0; m < 2; ++m)
                af[m] = *(bf16x8*)&Alds[(w * 32 + m * 16 + lr) * 64 + kb];
#pragma unroll
            for (int n = 0; n < 5; ++n)
                bfr[n] = *(bf16x8*)&Blds[(n * 16 + lr) * 64 + kb];
#pragma unroll
            for (int m = 0; m < 2; ++m)
#pragma unroll
                for (int n = 0; n < 5; ++n)
                    acc[m][n] = __builtin_amdgcn_mfma_f32_16x16x32_bf16(
                        af[m], bfr[n], acc[m][n], 0, 0, 0);
        }
        __syncthreads();
    }
    float* C = Cp2 + ((size_t)ks * BSZ + bm * 128) * NPAD;
#pragma unroll
    for (int m = 0; m < 2; ++m)
#pragma unroll
        for (int r = 0; r < 4; ++r) {
            const int i = w * 32 + m * 16 + lg * 4 + r;
#pragma unroll
            for (int n = 0; n < 5; ++n)
                C[(size_t)i * NPAD + n * 16 + lr] = acc[m][n][r];
        }
}

template<int KS>
__global__ __launch_bounds__(256, 2)
void gemm_relu_f32(const float* __restrict__ A, const float* __restrict__ B,
                   const float* __restrict__ bias, float* __restrict__ Cpart,
                   float* __restrict__ colsum)
{
    __shared__ __align__(16) short Alds[128 * 64];
    __shared__ __align__(16) short Blds[128 * 64];
    const int t  = threadIdx.x;
    const int bm = blockIdx.x, bn = blockIdx.y, ks = blockIdx.z;
    const int nsteps = KSTEPS / KS;
    const int l  = t & 63, w = t >> 6;
    const int wr = w >> 1, wc = w & 1;
    const int lr = l & 15, lg = l >> 4;
    const int srow = t >> 3, scol = (t & 7) * 8;
    const int sswz = (srow & 7) * 8;
    const int rswz = (lr & 7) * 8;
    const float* ga = A + (size_t)(bm * 128 + srow) * KDIM + scol;
    const float* gb = B + (size_t)(bn * 128 + srow) * KDIM + scol;
    f32x4 acc[4][4];
#pragma unroll
    for (int m = 0; m < 4; ++m)
#pragma unroll
        for (int n = 0; n < 4; ++n) acc[m][n] = (f32x4){0.f,0.f,0.f,0.f};
    for (int step = 0; step < nsteps; ++step) {
        const int k0 = (ks * nsteps + step) * 64;
#pragma unroll
        for (int p = 0; p < 4; ++p)
            *(bf16x8*)&Alds[(p * 32 + srow) * 64 + (scol ^ sswz)] =
                cvt8(ga + (size_t)(p * 32) * KDIM + k0);
#pragma unroll
        for (int p = 0; p < 4; ++p)
            *(bf16x8*)&Blds[(p * 32 + srow) * 64 + (scol ^ sswz)] =
                cvt8(gb + (size_t)(p * 32) * KDIM + k0);
        __syncthreads();
#pragma unroll
        for (int kk = 0; kk < 2; ++kk) {
            const int kb = (kk * 32 + lg * 8) ^ rswz;
            bf16x8 af[4], bfr[4];
#pragma unroll
            for (int m = 0; m < 4; ++m)
                af[m] = *(bf16x8*)&Alds[(wr * 64 + m * 16 + lr) * 64 + kb];
#pragma unroll
            for (int n = 0; n < 4; ++n)
                bfr[n] = *(bf16x8*)&Blds[(wc * 64 + n * 16 + lr) * 64 + kb];
#pragma unroll
            for (int m = 0; m < 4; ++m)
#pragma unroll
                for (int n = 0; n < 4; ++n)
                    acc[m][n] = __builtin_amdgcn_mfma_f32_16x16x32_bf16(
                        af[m], bfr[n], acc[m][n], 0, 0, 0);
        }
        __syncthreads();
    }
    if constexpr (KS == 1) {
        __shared__ float cls[128];
        if (t < 128) cls[t] = 0.f;
        __syncthreads();
#pragma unroll
        for (int n = 0; n < 4; ++n) {
            const int o = wc * 64 + n * 16 + lr;
            const float bv = bias[bn * 128 + o];
            float ps = 0.f;
#pragma unroll
            for (int m = 0; m < 4; ++m)
#pragma unroll
                for (int r = 0; r < 4; ++r) {
                    float v = acc[m][n][r] + bv;
                    ps += v > 0.f ? v : 0.f;
                }
            atomicAdd(&cls[o], ps);
        }
        __syncthreads();
        if (t < 128) atomicAdd(&colsum[bn * 128 + t], cls[t]);
    } else {
        float* Cp = Cpart + ((size_t)ks * BSZ + bm * 128) * NPROJ + bn * 128;
#pragma unroll
        for (int m = 0; m < 4; ++m)
#pragma unroll
            for (int r = 0; r < 4; ++r) {
                const int i = wr * 64 + m * 16 + lg * 4 + r;
#pragma unroll
                for (int n = 0; n < 4; ++n)
                    Cp[(size_t)i * NPROJ + wc * 64 + n * 16 + lr] = acc[m][n][r];
            }
    }
}

__global__ __launch_bounds__(256)
void fc1_kernel(const float* __restrict__ z1, const float* __restrict__ Wfc,
                const float* __restrict__ sconst, float* __restrict__ out)
{
    const int l = threadIdx.x & 63;
    const int w = threadIdx.x >> 6;
    const int i = blockIdx.x * 4 + w;
    const float* zr = z1 + (size_t)i * D1;
    float4 za[8];
#pragma unroll
    for (int j = 0; j < 8; ++j)
        za[j] = *(const float4*)&zr[j * 256 + l * 4];
    for (int c = 0; c < NCLS; ++c) {
        const float* wrow = Wfc + (size_t)c * DFC;
        float acc = 0.f;
#pragma unroll
        for (int j = 0; j < 8; ++j) {
            float4 wv = *(const float4*)&wrow[j * 256 + l * 4];
            acc += za[j].x * wv.x + za[j].y * wv.y + za[j].z * wv.z + za[j].w * wv.w;
        }
#pragma unroll
        for (int off = 32; off; off >>= 1)
            acc += __shfl_xor(acc, off);
        if (l == 0) out[(size_t)i * NCLS + c] = 2048.0f * acc + sconst[c];
    }
}

extern "C" void kernel_launch(void* const* d_in, const int* in_sizes, int n_in,
                              void* d_out, int out_size, void* d_ws, size_t ws_size,
                              hipStream_t stream)
{
    (void)in_sizes; (void)n_in; (void)out_size;
    const float* z1  = (const float*)d_in[0];
    const float* z2  = (const float*)d_in[1];
    const float* Wp  = (const float*)d_in[2];
    const float* bp  = (const float*)d_in[3];
    const float* Wf  = (const float*)d_in[4];
    const float* bfc = (const float*)d_in[5];
    float* out = (float*)d_out;

    float* colsum = (float*)d_ws;                 // 1024 f32
    float* sconst = (float*)d_ws + 1024;          // 65 f32
    size_t off = 8192;

    const size_t w1_sz   = (size_t)NPAD * D1 * 2;          // 0.33 MB
    const size_t c2_sz   = (size_t)16 * BSZ * NPAD * 4;    // 10.5 MB
    const size_t z2bf_sz = (size_t)BSZ * KDIM * 2;         // 38.5 MB
    const size_t wp_sz   = (size_t)NPROJ * KDIM * 2;       // 19.3 MB
    const size_t perKS   = (size_t)BSZ * NPROJ * 4;        // 8 MB

    const size_t needA = off + w1_sz + c2_sz + z2bf_sz + wp_sz + 7 * perKS;

    if (ws_size >= needA) {
        // ---------------- fused fast path (5 launches) ----------------
        short* W1    = (short*)((char*)d_ws + off);
        float* Cp2   = (float*)((char*)d_ws + off + w1_sz);
        short* z2bf  = (short*)((char*)d_ws + off + w1_sz + c2_sz);
        short* wpbf  = (short*)((char*)d_ws + off + w1_sz + c2_sz + z2bf_sz);
        float* Cpart = (float*)((char*)d_ws + off + w1_sz + c2_sz + z2bf_sz + wp_sz);

        fused_cvt<<<2048, 256, 0, stream>>>(z2, z2bf, Wp, wpbf, Wf, W1, (float*)d_ws);
        gemm_combo<7><<<896 + 256, 256, 0, stream>>>(z2bf, wpbf, Cpart, z1, W1, Cp2);
        reduce_colsum<7><<<dim3(128, 4), 256, 0, stream>>>(Cpart, bp, colsum);
        sconst_kernel<<<65, 64, 0, stream>>>(colsum, Wf, bfc, sconst);
        reduce2_kernel<16><<<1024, 256, 0, stream>>>(Cp2, sconst, out);
        return;
    }

    // ---------------- fallback tiers (R4-validated) ----------------
    hipMemsetAsync(d_ws, 0, 8192, stream);

    const bool fc2_ok = ws_size >= off + w1_sz + c2_sz;
    short* W1  = (short*)((char*)d_ws + off);
    float* Cp2 = (float*)((char*)d_ws + off + w1_sz);
    if (fc2_ok) off += w1_sz + c2_sz;
    const size_t rem = ws_size > off ? ws_size - off : 0;

    int main_ks = 0;
    if      (rem >= z2bf_sz + wp_sz + 3 * perKS) main_ks = 3;
    else if (rem >= z2bf_sz + wp_sz + 1 * perKS) main_ks = 1;

    if (main_ks > 0) {
        short* z2bf  = (short*)((char*)d_ws + off);
        short* wpbf  = (short*)((char*)d_ws + off + z2bf_sz);
        float* Cpart = (float*)((char*)d_ws + off + z2bf_sz + wp_sz);
        cvt_bf16<<<2048, 256, 0, stream>>>(z2, z2bf, BSZ * KDIM / 8);
        cvt_bf16<<<1024, 256, 0, stream>>>(Wp, wpbf, NPROJ * KDIM / 8);
        if (main_ks == 3) {
            gemm_bf16<3><<<384, 256, 0, stream>>>(z2bf, wpbf, Cpart);
            reduce_colsum<3><<<dim3(128, 4), 256, 0, stream>>>(Cpart, bp, colsum);
        } else {
            gemm_bf16<1><<<128, 256, 0, stream>>>(z2bf, wpbf, Cpart);
            reduce_colsum<1><<<dim3(128, 4), 256, 0, stream>>>(Cpart, bp, colsum);
        }
    } else if (rem >= 7 * perKS) {
        float* Cpart = (float*)((char*)d_ws + off);
        gemm_relu_f32<7><<<dim3(16, 8, 7), 256, 0, stream>>>(z2, Wp, bp, Cpart, colsum);
        reduce_colsum<7><<<dim3(128, 4), 256, 0, stream>>>(Cpart, bp, colsum);
    } else {
        gemm_relu_f32<1><<<dim3(16, 8, 1), 256, 0, stream>>>(z2, Wp, bp,
                                                             (float*)((char*)d_ws + off), colsum);
    }

    sconst_kernel<<<65, 64, 0, stream>>>(colsum, Wf, bfc, sconst);

    if (fc2_ok) {
        w1pad_kernel<<<80, 256, 0, stream>>>(Wf, W1);
        fc2_gemm<16><<<256, 256, 0, stream>>>(z1, W1, Cp2);
        reduce2_kernel<16><<<1024, 256, 0, stream>>>(Cp2, sconst, out);
    } else {
        fc1_kernel<<<512, 256, 0, stream>>>(z1, Wf, sconst, out);
    }
}